// Round 3
// baseline (87.575 us; speedup 1.0000x reference)
//
#include <hip/hip_runtime.h>

// Encoder: out[p, 0:300]   = batch[p] < 20000 ? vectors[batch[p], :] : 0
//          out[p, 300:556] = b[:] + (batch[p] >= 20000 ? W[:, batch[p]-20000] : 0)
// Pure gather — the one-hot einsum selects a single column of W. No matmul.
// fp32 throughout (R1 post-mortem). R3: float4 x1 path, 8 tokens/block for
// ILP-based latency hiding, hoisted bias load.

#define N_PRE 20000
#define VEC_DIM 300
#define INPUT_SIZE 10000
#define HIDDEN 256
#define OUT_DIM (VEC_DIM + HIDDEN)   // 556 floats = 2224 B per row, 16B-aligned
#define VEC4 (VEC_DIM / 4)           // 75 float4 per vectors row (1200 B, 16B-aligned)
#define TOK_PER_BLK 8

__global__ __launch_bounds__(256) void encoder_gather_kernel(
    const int* __restrict__ batch,        // [n_tokens]
    const float4* __restrict__ vectors4,  // [20000][75] float4 view
    const float* __restrict__ W,          // [256, 10000] row-major
    const float* __restrict__ b,          // [256]
    float* __restrict__ out,              // [n_tokens, 556]
    int n_tokens)
{
    const int tid  = threadIdx.x;
    const int base = blockIdx.x * TOK_PER_BLK;

    // bias is token-invariant: load once per thread (block=256 == HIDDEN)
    const float bias = b[tid];

#pragma unroll
    for (int j = 0; j < TOK_PER_BLK; ++j) {
        const int p = base + j;
        if (p >= n_tokens) break;        // uniform guard (4096 % 8 == 0 anyway)
        const int t = batch[p];          // wave-uniform -> scalar load
        float* orow = out + (size_t)p * OUT_DIM;

        // --- x1: 75 float4 (threads 0..74), coalesced ---
        if (tid < VEC4) {
            float4 v = make_float4(0.f, 0.f, 0.f, 0.f);
            if (t < N_PRE) {
                v = vectors4[(size_t)t * VEC4 + tid];
            }
            ((float4*)orow)[tid] = v;
        }

        // --- x2: one W column element per thread + bias, coalesced store ---
        float acc = bias;
        if (t >= N_PRE) {
            acc += W[(size_t)tid * INPUT_SIZE + (t - N_PRE)];
        }
        orow[VEC_DIM + tid] = acc;
    }
}

extern "C" void kernel_launch(void* const* d_in, const int* in_sizes, int n_in,
                              void* d_out, int out_size, void* d_ws, size_t ws_size,
                              hipStream_t stream) {
    const int* batch        = (const int*)d_in[0];
    const float4* vectors4  = (const float4*)d_in[1];
    const float* W          = (const float*)d_in[2];
    const float* b          = (const float*)d_in[3];
    float* out              = (float*)d_out;

    const int n_tokens = in_sizes[0];  // 8 * 512 = 4096
    const int grid = (n_tokens + TOK_PER_BLK - 1) / TOK_PER_BLK;

    encoder_gather_kernel<<<grid, 256, 0, stream>>>(
        batch, vectors4, W, b, out, n_tokens);
}